// Round 5
// baseline (389.364 us; speedup 1.0000x reference)
//
#include <hip/hip_runtime.h>
#include <hip/hip_bf16.h>

#define NN 6144
#define INPUT 1024
#define HID 256

using frag  = __attribute__((ext_vector_type(8))) short;   // 8 bf16
using f32x4 = __attribute__((ext_vector_type(4))) float;

union FU { frag f; unsigned u[4]; };

static __device__ __forceinline__ unsigned short bf16u(float x) {
    unsigned u = __float_as_uint(x);
    u += 0x7fff + ((u >> 16) & 1);     // RNE
    return (unsigned short)(u >> 16);
}

// pack 2 f32 -> 2 bf16 in one inst (RNE) — T12 recipe, no builtin on gfx950
static __device__ __forceinline__ unsigned cvtpk(float lo, float hi) {
    unsigned r;
    asm("v_cvt_pk_bf16_f32 %0, %1, %2" : "=v"(r) : "v"(lo), "v"(hi));
    return r;
}

// ---------------- prep: X -> Xb bf16 (row-major), W -> Wt bf16 transposed ----------------
__global__ __launch_bounds__(256) void k_prep(const float* __restrict__ X,
                                              const float* __restrict__ W,
                                              unsigned short* __restrict__ Xb,
                                              unsigned short* __restrict__ Wt) {
    int b = blockIdx.x;
    if (b < 3072) {                         // X: 6144*1024 f32, 8 per thread
        int t = b * 256 + threadIdx.x;
        const float4* p = reinterpret_cast<const float4*>(X) + (size_t)t * 2;
        float4 x0 = p[0], x1 = p[1];
        frag v;
        v[0] = (short)bf16u(x0.x); v[1] = (short)bf16u(x0.y);
        v[2] = (short)bf16u(x0.z); v[3] = (short)bf16u(x0.w);
        v[4] = (short)bf16u(x1.x); v[5] = (short)bf16u(x1.y);
        v[6] = (short)bf16u(x1.z); v[7] = (short)bf16u(x1.w);
        *reinterpret_cast<frag*>(Xb + (size_t)t * 8) = v;
    } else {                                // W transpose: t = n*1024 + k
        int t = (b - 3072) * 256 + threadIdx.x;
        int n = t >> 10, k = t & 1023;
        Wt[t] = bf16u(W[k * HID + n]);
    }
}

// ---------------- GEMM1: hT = (Xb @ W)^T bf16, + fused s1/s2 ----------------
// BARRIER-FREE, LDS-FREE. grid (192,4); block 256 = 4 waves, fully independent.
// Wave: M=32 (rows i0+lm, i0+16+lm), N=16 (n0 = by*64 + w*16), K=1024 = 32 steps,
// depth-1 register ping-pong. All 4 waves read the SAME Xb rows -> L1 absorbs the
// intra-block redundancy. ~50 VGPR, 3 balanced blocks/CU (fixes r3's failure).
__global__ __launch_bounds__(256, 4) void k_gemm1(const unsigned short* __restrict__ Xb,
                                                  const unsigned short* __restrict__ Wt,
                                                  const float* __restrict__ a_edge,
                                                  unsigned short* __restrict__ hT,
                                                  float* __restrict__ s1,
                                                  float* __restrict__ s2) {
    int t = threadIdx.x;
    int w = t >> 6, l = t & 63, lm = l & 15, q = l >> 4;
    int i0 = blockIdx.x * 32;
    int n0 = blockIdx.y * 64 + w * 16;

    const unsigned short* arow0 = Xb + (size_t)(i0 + lm) * INPUT + q * 8;
    const unsigned short* arow1 = arow0 + 16 * INPUT;
    const unsigned short* brow  = Wt + (size_t)(n0 + lm) * INPUT + q * 8;

    f32x4 acc0 = {}, acc1 = {};
    frag A0[2], A1[2], B[2];
    A0[0] = *reinterpret_cast<const frag*>(arow0);
    A1[0] = *reinterpret_cast<const frag*>(arow1);
    B[0]  = *reinterpret_cast<const frag*>(brow);

#pragma unroll
    for (int ks = 0; ks < 32; ks++) {
        int cur = ks & 1, nxt = cur ^ 1;
        if (ks < 31) {
            A0[nxt] = *reinterpret_cast<const frag*>(arow0 + (ks + 1) * 32);
            A1[nxt] = *reinterpret_cast<const frag*>(arow1 + (ks + 1) * 32);
            B[nxt]  = *reinterpret_cast<const frag*>(brow + (ks + 1) * 32);
        }
        acc0 = __builtin_amdgcn_mfma_f32_16x16x32_bf16(A0[cur], B[cur], acc0, 0, 0, 0);
        acc1 = __builtin_amdgcn_mfma_f32_16x16x32_bf16(A1[cur], B[cur], acc1, 0, 0, 0);
    }

    // hT write: C/D layout col=lm (n), row=q*4+r (m within 16-half)
    ushort4 o;
    o.x = bf16u(acc0[0]); o.y = bf16u(acc0[1]); o.z = bf16u(acc0[2]); o.w = bf16u(acc0[3]);
    *reinterpret_cast<ushort4*>(hT + (size_t)(n0 + lm) * NN + i0 + q * 4) = o;
    o.x = bf16u(acc1[0]); o.y = bf16u(acc1[1]); o.z = bf16u(acc1[2]); o.w = bf16u(acc1[3]);
    *reinterpret_cast<ushort4*>(hT + (size_t)(n0 + lm) * NN + i0 + 16 + q * 4) = o;

    // fused s1/s2: reduce over the 16 n of this wave's slice, few atomics
    float a1v = a_edge[n0 + lm], a2v = a_edge[HID + n0 + lm];
#pragma unroll
    for (int h = 0; h < 2; h++) {
        const f32x4& ac = h ? acc1 : acc0;
#pragma unroll
        for (int r = 0; r < 4; r++) {
            float v1 = ac[r] * a1v, v2 = ac[r] * a2v;
            v1 += __shfl_xor(v1, 1); v2 += __shfl_xor(v2, 1);
            v1 += __shfl_xor(v1, 2); v2 += __shfl_xor(v2, 2);
            v1 += __shfl_xor(v1, 4); v2 += __shfl_xor(v2, 4);
            v1 += __shfl_xor(v1, 8); v2 += __shfl_xor(v2, 8);
            if (lm == 0) {
                atomicAdd(&s1[i0 + h * 16 + q * 4 + r], v1);
                atomicAdd(&s2[i0 + h * 16 + q * 4 + r], v2);
            }
        }
    }
}

// ---------------- fused attention: NO LDS, NO BARRIERS ----------------
// grid (192,4); block 256 = 4 waves = 4 n-quarters (nq). Every wave independent.
// Wave: M=32 rows (lm, lm+16), N=64 (nq*64, 4 nt-frags), j-quarter 1536 = 48 steps.
// Each lane COMPUTES its own A-fragment (P values) in registers: MFMA A-layout is
// row=lane&15, k=(lane>>4)*8+e, so lane (lm,q) needs exactly adj[row][j+q*8..+7] --
// the load lands where it's consumed. P is computed 4x redundantly (one per nq wave),
// paid in VALU (cheap, spread over 1024 SIMDs) to buy: zero phase coupling between
// waves, so TLP + depth-1 ping-pong hides all latency. adj reads L1-shared within
// the block (4 waves, same rows).
__global__ __launch_bounds__(256, 3) void k_attn(const int* __restrict__ adj,
                                                 const float* __restrict__ s1,
                                                 const float* __restrict__ s2,
                                                 const unsigned short* __restrict__ hT,
                                                 float* __restrict__ U4,
                                                 float* __restrict__ denom4) {
    int t = threadIdx.x;
    int nq = t >> 6, l = t & 63, lm = l & 15, q = l >> 4;
    int i0 = blockIdx.x * 32;
    int q4 = blockIdx.y;
    int j0 = q4 * 1536;

    float s1v0 = s1[i0 + lm], s1v1 = s1[i0 + 16 + lm];
    const int*   arow0 = adj + (size_t)(i0 + lm) * NN + j0 + q * 8;
    const int*   arow1 = arow0 + (size_t)16 * NN;
    const float* s2p   = s2 + j0 + q * 8;
    const unsigned short* bp0 = hT + (size_t)(nq * 64 + 0 * 16 + lm) * NN + j0 + q * 8;
    const unsigned short* bp1 = hT + (size_t)(nq * 64 + 1 * 16 + lm) * NN + j0 + q * 8;
    const unsigned short* bp2 = hT + (size_t)(nq * 64 + 2 * 16 + lm) * NN + j0 + q * 8;
    const unsigned short* bp3 = hT + (size_t)(nq * 64 + 3 * 16 + lm) * NN + j0 + q * 8;

    f32x4 acc[2][4] = {};
    float dsL = 0.f, dsH = 0.f;

    int4   AL0[2], AL1[2], AH0[2], AH1[2];
    float4 S0[2], S1[2];
    frag   Bf[2][4];

#define LOADSTEP(KS, SET)                                                     \
    {                                                                         \
        AL0[SET] = *reinterpret_cast<const int4*>(arow0 + (KS) * 32);         \
        AL1[SET] = *reinterpret_cast<const int4*>(arow0 + (KS) * 32 + 4);     \
        AH0[SET] = *reinterpret_cast<const int4*>(arow1 + (KS) * 32);         \
        AH1[SET] = *reinterpret_cast<const int4*>(arow1 + (KS) * 32 + 4);     \
        S0[SET]  = *reinterpret_cast<const float4*>(s2p + (KS) * 32);         \
        S1[SET]  = *reinterpret_cast<const float4*>(s2p + (KS) * 32 + 4);     \
        Bf[SET][0] = *reinterpret_cast<const frag*>(bp0 + (KS) * 32);         \
        Bf[SET][1] = *reinterpret_cast<const frag*>(bp1 + (KS) * 32);         \
        Bf[SET][2] = *reinterpret_cast<const frag*>(bp2 + (KS) * 32);         \
        Bf[SET][3] = *reinterpret_cast<const frag*>(bp3 + (KS) * 32);         \
    }

#define COMPUTE(SET)                                                                          \
    {                                                                                         \
        float sc, wv, pa, pb;                                                                 \
        FU fL, fH;                                                                            \
        sc = s1v0 + S0[SET].x; wv = fmaxf(sc, 0.2f * sc); pa = AL0[SET].x ? __expf(wv) : 0.f; \
        sc = s1v0 + S0[SET].y; wv = fmaxf(sc, 0.2f * sc); pb = AL0[SET].y ? __expf(wv) : 0.f; \
        dsL += pa + pb; fL.u[0] = cvtpk(pa, pb);                                              \
        sc = s1v0 + S0[SET].z; wv = fmaxf(sc, 0.2f * sc); pa = AL0[SET].z ? __expf(wv) : 0.f; \
        sc = s1v0 + S0[SET].w; wv = fmaxf(sc, 0.2f * sc); pb = AL0[SET].w ? __expf(wv) : 0.f; \
        dsL += pa + pb; fL.u[1] = cvtpk(pa, pb);                                              \
        sc = s1v0 + S1[SET].x; wv = fmaxf(sc, 0.2f * sc); pa = AL1[SET].x ? __expf(wv) : 0.f; \
        sc = s1v0 + S1[SET].y; wv = fmaxf(sc, 0.2f * sc); pb = AL1[SET].y ? __expf(wv) : 0.f; \
        dsL += pa + pb; fL.u[2] = cvtpk(pa, pb);                                              \
        sc = s1v0 + S1[SET].z; wv = fmaxf(sc, 0.2f * sc); pa = AL1[SET].z ? __expf(wv) : 0.f; \
        sc = s1v0 + S1[SET].w; wv = fmaxf(sc, 0.2f * sc); pb = AL1[SET].w ? __expf(wv) : 0.f; \
        dsL += pa + pb; fL.u[3] = cvtpk(pa, pb);                                              \
        sc = s1v1 + S0[SET].x; wv = fmaxf(sc, 0.2f * sc); pa = AH0[SET].x ? __expf(wv) : 0.f; \
        sc = s1v1 + S0[SET].y; wv = fmaxf(sc, 0.2f * sc); pb = AH0[SET].y ? __expf(wv) : 0.f; \
        dsH += pa + pb; fH.u[0] = cvtpk(pa, pb);                                              \
        sc = s1v1 + S0[SET].z; wv = fmaxf(sc, 0.2f * sc); pa = AH0[SET].z ? __expf(wv) : 0.f; \
        sc = s1v1 + S0[SET].w; wv = fmaxf(sc, 0.2f * sc); pb = AH0[SET].w ? __expf(wv) : 0.f; \
        dsH += pa + pb; fH.u[1] = cvtpk(pa, pb);                                              \
        sc = s1v1 + S1[SET].x; wv = fmaxf(sc, 0.2f * sc); pa = AH1[SET].x ? __expf(wv) : 0.f; \
        sc = s1v1 + S1[SET].y; wv = fmaxf(sc, 0.2f * sc); pb = AH1[SET].y ? __expf(wv) : 0.f; \
        dsH += pa + pb; fH.u[2] = cvtpk(pa, pb);                                              \
        sc = s1v1 + S1[SET].z; wv = fmaxf(sc, 0.2f * sc); pa = AH1[SET].z ? __expf(wv) : 0.f; \
        sc = s1v1 + S1[SET].w; wv = fmaxf(sc, 0.2f * sc); pb = AH1[SET].w ? __expf(wv) : 0.f; \
        dsH += pa + pb; fH.u[3] = cvtpk(pa, pb);                                              \
        acc[0][0] = __builtin_amdgcn_mfma_f32_16x16x32_bf16(fL.f, Bf[SET][0], acc[0][0], 0, 0, 0); \
        acc[1][0] = __builtin_amdgcn_mfma_f32_16x16x32_bf16(fH.f, Bf[SET][0], acc[1][0], 0, 0, 0); \
        acc[0][1] = __builtin_amdgcn_mfma_f32_16x16x32_bf16(fL.f, Bf[SET][1], acc[0][1], 0, 0, 0); \
        acc[1][1] = __builtin_amdgcn_mfma_f32_16x16x32_bf16(fH.f, Bf[SET][1], acc[1][1], 0, 0, 0); \
        acc[0][2] = __builtin_amdgcn_mfma_f32_16x16x32_bf16(fL.f, Bf[SET][2], acc[0][2], 0, 0, 0); \
        acc[1][2] = __builtin_amdgcn_mfma_f32_16x16x32_bf16(fH.f, Bf[SET][2], acc[1][2], 0, 0, 0); \
        acc[0][3] = __builtin_amdgcn_mfma_f32_16x16x32_bf16(fL.f, Bf[SET][3], acc[0][3], 0, 0, 0); \
        acc[1][3] = __builtin_amdgcn_mfma_f32_16x16x32_bf16(fH.f, Bf[SET][3], acc[1][3], 0, 0, 0); \
    }

    LOADSTEP(0, 0)
    for (int it = 0; it < 23; ++it) {
#pragma unroll
        for (int sub = 0; sub < 2; ++sub) {
            int ks = it * 2 + sub;           // runtime; only load offsets use it
            LOADSTEP(ks + 1, sub ^ 1)        // steps 1..46
            COMPUTE(sub)                     // steps 0..45
        }
    }
    LOADSTEP(47, 1)
    COMPUTE(0)                               // step 46
    COMPUTE(1)                               // step 47
#undef LOADSTEP
#undef COMPUTE

    // denominator partials: lane (lm,q) holds row lm / row 16+lm partial over its
    // q-interleaved j-slices; reduce over q (lanes differing in bits 4,5).
    dsL += __shfl_xor(dsL, 16); dsL += __shfl_xor(dsL, 32);
    dsH += __shfl_xor(dsH, 16); dsH += __shfl_xor(dsH, 32);
    if (nq == 0 && q == 0) {
        denom4[(size_t)q4 * NN + i0 + lm]      = dsL;
        denom4[(size_t)q4 * NN + i0 + 16 + lm] = dsH;
    }

    // U4 partial: plain stores (no atomics)
    float* Ub = U4 + (size_t)q4 * NN * HID;
#pragma unroll
    for (int h = 0; h < 2; h++)
#pragma unroll
        for (int nt = 0; nt < 4; nt++)
#pragma unroll
            for (int r = 0; r < 4; r++)
                Ub[(size_t)(i0 + h * 16 + q * 4 + r) * HID + nq * 64 + nt * 16 + lm] = acc[h][nt][r];
}

// ---------------- normalize: out = (sum_q U4) / (sum_q denom4) ----------------
__global__ __launch_bounds__(256) void k_norm(const float* __restrict__ U4,
                                              const float* __restrict__ denom4,
                                              float* __restrict__ out) {
    int i = blockIdx.x, t = threadIdx.x;
    size_t S = (size_t)NN * HID;
    size_t base = (size_t)i * HID + t;
    float u = U4[base] + U4[base + S] + U4[base + 2 * S] + U4[base + 3 * S];
    float d = denom4[i] + denom4[i + NN] + denom4[i + 2 * NN] + denom4[i + 3 * NN];
    out[base] = (d != 0.f) ? u / d : 0.f;
}

extern "C" void kernel_launch(void* const* d_in, const int* in_sizes, int n_in,
                              void* d_out, int out_size, void* d_ws, size_t ws_size,
                              hipStream_t stream) {
    const float* X      = (const float*)d_in[0];   // 6144x1024
    const float* W      = (const float*)d_in[1];   // 1024x256
    const float* a_edge = (const float*)d_in[2];   // 512
    const int*   adj    = (const int*)d_in[3];     // 6144x6144
    float* out = (float*)d_out;

    float* U4     = (float*)d_ws;                          // 4*NN*HID f32 (25.2 MB)
    float* denom4 = U4 + (size_t)4 * NN * HID;             // 4*NN
    float* s1     = denom4 + (size_t)4 * NN;               // NN
    float* s2     = s1 + NN;                               // NN
    unsigned short* hT = (unsigned short*)(s2 + NN);       // HID*NN bf16 (3.1 MB)
    unsigned short* Wt = hT + (size_t)HID * NN;            // HID*INPUT bf16 (0.5 MB)
    // Xb (12.6 MB) ALIASES U4: dead before k_attn fully overwrites U4.
    unsigned short* Xb = (unsigned short*)U4;

    hipMemsetAsync(s1, 0, 2 * NN * sizeof(float), stream);
    k_prep<<<3072 + INPUT * HID / 256, 256, 0, stream>>>(X, W, Xb, Wt);
    k_gemm1<<<dim3(NN / 32, 4), 256, 0, stream>>>(Xb, Wt, a_edge, hT, s1, s2);
    k_attn<<<dim3(NN / 32, 4), 256, 0, stream>>>(adj, s1, s2, hT, U4, denom4);
    k_norm<<<NN, 256, 0, stream>>>(U4, denom4, out);
}

// Round 6
// 307.184 us; speedup vs baseline: 1.2675x; 1.2675x over previous
//
#include <hip/hip_runtime.h>
#include <hip/hip_bf16.h>

#define NN 6144
#define INPUT 1024
#define HID 256

using frag  = __attribute__((ext_vector_type(8))) short;   // 8 bf16
using f32x4 = __attribute__((ext_vector_type(4))) float;

static __device__ __forceinline__ unsigned short bf16u(float x) {
    unsigned u = __float_as_uint(x);
    u += 0x7fff + ((u >> 16) & 1);     // RNE
    return (unsigned short)(u >> 16);
}

// async global->LDS, 16B/lane and 4B/lane. No VGPR dest: the compiler cannot
// sink these, and consumption is gated by OUR counted vmcnt (in-order retirement:
// gll ops issued oldest retire first).
static __device__ __forceinline__ void gll16(const void* g, void* l) {
    __builtin_amdgcn_global_load_lds((__attribute__((address_space(1))) const void*)g,
                                     (__attribute__((address_space(3))) void*)l, 16, 0, 0);
}
static __device__ __forceinline__ void gll4(const void* g, void* l) {
    __builtin_amdgcn_global_load_lds((__attribute__((address_space(1))) const void*)g,
                                     (__attribute__((address_space(3))) void*)l, 4, 0, 0);
}

// LDS-producer barrier without the __syncthreads vmcnt(0) drain.
static __device__ __forceinline__ void lds_barrier() {
    asm volatile("s_waitcnt lgkmcnt(0)" ::: "memory");
    __builtin_amdgcn_s_barrier();
    __builtin_amdgcn_sched_barrier(0);
}

// ---------------- prep: X -> Xb bf16 (row-major), W -> Wt bf16 transposed ----------------
__global__ __launch_bounds__(256) void k_prep(const float* __restrict__ X,
                                              const float* __restrict__ W,
                                              unsigned short* __restrict__ Xb,
                                              unsigned short* __restrict__ Wt) {
    int b = blockIdx.x;
    if (b < 3072) {                         // X: 6144*1024 f32, 8 per thread
        int t = b * 256 + threadIdx.x;
        const float4* p = reinterpret_cast<const float4*>(X) + (size_t)t * 2;
        float4 x0 = p[0], x1 = p[1];
        frag v;
        v[0] = (short)bf16u(x0.x); v[1] = (short)bf16u(x0.y);
        v[2] = (short)bf16u(x0.z); v[3] = (short)bf16u(x0.w);
        v[4] = (short)bf16u(x1.x); v[5] = (short)bf16u(x1.y);
        v[6] = (short)bf16u(x1.z); v[7] = (short)bf16u(x1.w);
        *reinterpret_cast<frag*>(Xb + (size_t)t * 8) = v;
    } else {                                // W transpose: t = n*1024 + k
        int t = (b - 3072) * 256 + threadIdx.x;
        int n = t >> 10, k = t & 1023;
        Wt[t] = bf16u(W[k * HID + n]);
    }
}

// ---------------- GEMM1: hT = (Xb @ W)^T bf16, + fused s1/s2 ----------------
// grid (192,4); block 256 = 4 waves. BK=128 -> 8 chunks (half the barriers of r2).
// A-tile staged by global_load_lds (async, zero VGPR) with XOR-swizzled SOURCE
// (LDS dest must stay linear: m104). Read side applies the same XOR -> no 16-way
// bank conflict. Counted vmcnt(4) before the barrier keeps next-chunk staging and
// B-frag loads in flight (never drains).
__global__ __launch_bounds__(256, 4) void k_gemm1(const unsigned short* __restrict__ Xb,
                                                  const unsigned short* __restrict__ Wt,
                                                  const float* __restrict__ a_edge,
                                                  unsigned short* __restrict__ hT,
                                                  float* __restrict__ s1,
                                                  float* __restrict__ s2) {
    __shared__ unsigned short A[2][32][128];   // 16 KiB, linear (gll dest)
    int t = threadIdx.x;
    int i0 = blockIdx.x * 32, n0 = blockIdx.y * 64;
    int w = t >> 6, l = t & 63, lm = l & 15, q = l >> 4;
    int nw = n0 + w * 16;

    const unsigned short* brow = Wt + (size_t)(nw + lm) * INPUT + q * 8;

    // staging: wave w stages rows w*8..w*8+7; instr covers 4 rows (64 lanes x 16B).
    // lane l -> row +(l>>4), granule g=(l&15); source col pre-XOR'd by (row&7).
    int r0 = w * 8 + (l >> 4);
    const unsigned short* xs0 = Xb + (size_t)(i0 + r0) * INPUT + (((l & 15) ^ (r0 & 7)) << 3);
    const unsigned short* xs1 = Xb + (size_t)(i0 + r0 + 4) * INPUT + (((l & 15) ^ ((r0 + 4) & 7)) << 3);

#define GSTAGE(C, BUF) { \
        gll16(xs0 + (C) * 128, &A[BUF][w * 8][0]); \
        gll16(xs1 + (C) * 128, &A[BUF][w * 8 + 4][0]); }

    f32x4 acc0 = {}, acc1 = {};
    GSTAGE(0, 0)

    for (int c = 0; c < 8; c++) {
        int buf = c & 1;
        frag b0 = *reinterpret_cast<const frag*>(brow + c * 128);
        frag b1 = *reinterpret_cast<const frag*>(brow + c * 128 + 32);
        frag b2 = *reinterpret_cast<const frag*>(brow + c * 128 + 64);
        frag b3 = *reinterpret_cast<const frag*>(brow + c * 128 + 96);
        // outstanding: gll(c)[2, oldest] + B[4] = 6 -> vmcnt(4) retires exactly gll(c)
        asm volatile("s_waitcnt vmcnt(4)" ::: "memory");
        __builtin_amdgcn_s_barrier();
        __builtin_amdgcn_sched_barrier(0);
        if (c < 7) GSTAGE(c + 1, buf ^ 1)      // after barrier: prev readers done

#pragma unroll
        for (int kk = 0; kk < 4; kk++) {
            int sw = (kk * 32 + q * 8) ^ ((lm & 7) << 3);
            frag a0 = *reinterpret_cast<const frag*>(&A[buf][lm][sw]);
            frag a1 = *reinterpret_cast<const frag*>(&A[buf][16 + lm][sw]);
            frag b  = (kk == 0) ? b0 : (kk == 1) ? b1 : (kk == 2) ? b2 : b3;
            acc0 = __builtin_amdgcn_mfma_f32_16x16x32_bf16(a0, b, acc0, 0, 0, 0);
            acc1 = __builtin_amdgcn_mfma_f32_16x16x32_bf16(a1, b, acc1, 0, 0, 0);
        }
    }
#undef GSTAGE

    // hT write: C/D layout col=lm (n), row=q*4+r (m within 16-half)
    ushort4 o;
    o.x = bf16u(acc0[0]); o.y = bf16u(acc0[1]); o.z = bf16u(acc0[2]); o.w = bf16u(acc0[3]);
    *reinterpret_cast<ushort4*>(hT + (size_t)(nw + lm) * NN + i0 + q * 4) = o;
    o.x = bf16u(acc1[0]); o.y = bf16u(acc1[1]); o.z = bf16u(acc1[2]); o.w = bf16u(acc1[3]);
    *reinterpret_cast<ushort4*>(hT + (size_t)(nw + lm) * NN + i0 + 16 + q * 4) = o;

    // fused s1/s2
    float a1v = a_edge[nw + lm], a2v = a_edge[HID + nw + lm];
#pragma unroll
    for (int h = 0; h < 2; h++) {
        const f32x4& ac = h ? acc1 : acc0;
#pragma unroll
        for (int r = 0; r < 4; r++) {
            float v1 = ac[r] * a1v, v2 = ac[r] * a2v;
            v1 += __shfl_xor(v1, 1); v2 += __shfl_xor(v2, 1);
            v1 += __shfl_xor(v1, 2); v2 += __shfl_xor(v2, 2);
            v1 += __shfl_xor(v1, 4); v2 += __shfl_xor(v2, 4);
            v1 += __shfl_xor(v1, 8); v2 += __shfl_xor(v2, 8);
            if (lm == 0) {
                atomicAdd(&s1[i0 + h * 16 + q * 4 + r], v1);
                atomicAdd(&s2[i0 + h * 16 + q * 4 + r], v2);
            }
        }
    }
}

// ---------------- fused attention ----------------
// grid (192,4); block 512 = 8 waves; r2 skeleton. adj+s2 staged ONE chunk ahead by
// global_load_lds (3 ops/wave/chunk, zero VGPR -- allocator can't sink them).
// Per chunk: [issue 8 bf] [vmcnt(8): retires gll(c) only, bf stays in flight]
// [barrier] [stage c+1] [build P from LDS] [lgkm barrier] [MFMA; compiler emits
// counted vmcnt(3) for bf, keeping gll(c+1) in flight]. vmcnt never drains to 0.
__global__ __launch_bounds__(512, 2) void k_attn(const int* __restrict__ adj,
                                                 const float* __restrict__ s1,
                                                 const float* __restrict__ s2,
                                                 const unsigned short* __restrict__ hT,
                                                 float* __restrict__ U4,
                                                 float* __restrict__ denom4) {
    __shared__ unsigned short P[2][32][136];   // 17408 B
    __shared__ int   adjS[2][32][128];         // 32768 B, linear (gll dest)
    __shared__ float s2S[2][128];              // 1024 B
    int t = threadIdx.x;
    int m = t >> 4, cg = t & 15;               // builder: row m (0..31), col-group cg
    int i0 = blockIdx.x * 32;
    int q4 = blockIdx.y, j0 = q4 * 1536;
    int w = t >> 6, l = t & 63, lm = l & 15, q = l >> 4;

    float s1v = s1[i0 + m];
    // staging: wave w stages adj rows w*4..w*4+3 (2 instrs x 2 rows) + 16 s2 floats
    const int*   astage = adj + (size_t)(i0 + w * 4 + (l >> 5)) * NN + j0 + (l & 31) * 4;
    const float* sstage = s2 + j0 + w * 16 + l;    // only lanes l<16 issue

    const unsigned short* brow[2];
#pragma unroll
    for (int nt = 0; nt < 2; nt++)
        brow[nt] = hT + (size_t)(w * 32 + nt * 16 + lm) * NN + j0 + q * 8;

    f32x4 acc[2][2] = {};
    float dsum = 0.f;

#define STAGE(JC, BUF) { \
        gll16(astage + (JC), &adjS[BUF][w * 4][0]); \
        gll16(astage + (JC) + 2 * NN, &adjS[BUF][w * 4 + 2][0]); \
        if (l < 16) gll4(sstage + (JC), &s2S[BUF][w * 16]); }

    STAGE(0, 0)

    for (int c = 0; c < 12; c++) {
        int buf = c & 1, jc = c * 128;

        frag bf[8];
#pragma unroll
        for (int kk = 0; kk < 4; kk++)
#pragma unroll
            for (int nt = 0; nt < 2; nt++)
                bf[kk * 2 + nt] = *reinterpret_cast<const frag*>(brow[nt] + jc + kk * 32);

        // outstanding: gll(c)[3, oldest] + bf[8] = 11 -> vmcnt(8) retires exactly gll(c)
        asm volatile("s_waitcnt vmcnt(8)" ::: "memory");
        __builtin_amdgcn_s_barrier();              // adjS[buf]/s2S[buf] ready block-wide
        __builtin_amdgcn_sched_barrier(0);
        if (c < 11) STAGE(jc + 128, buf ^ 1)       // after barrier: prev readers done

        // ---- build P[buf] from staged LDS (VALU only, no global waits) ----
        {
            const int*   aL = &adjS[buf][m][cg * 8];
            const float* sL = &s2S[buf][cg * 8];
            int4   av0 = *reinterpret_cast<const int4*>(aL);
            int4   av1 = *reinterpret_cast<const int4*>(aL + 4);
            float4 sv0 = *reinterpret_cast<const float4*>(sL);
            float4 sv1 = *reinterpret_cast<const float4*>(sL + 4);
            float sc, wv, p0, p1, p2, p3, p4, p5, p6, p7;
            sc = s1v + sv0.x; wv = fmaxf(sc, 0.2f * sc); p0 = av0.x ? __expf(wv) : 0.f;
            sc = s1v + sv0.y; wv = fmaxf(sc, 0.2f * sc); p1 = av0.y ? __expf(wv) : 0.f;
            sc = s1v + sv0.z; wv = fmaxf(sc, 0.2f * sc); p2 = av0.z ? __expf(wv) : 0.f;
            sc = s1v + sv0.w; wv = fmaxf(sc, 0.2f * sc); p3 = av0.w ? __expf(wv) : 0.f;
            sc = s1v + sv1.x; wv = fmaxf(sc, 0.2f * sc); p4 = av1.x ? __expf(wv) : 0.f;
            sc = s1v + sv1.y; wv = fmaxf(sc, 0.2f * sc); p5 = av1.y ? __expf(wv) : 0.f;
            sc = s1v + sv1.z; wv = fmaxf(sc, 0.2f * sc); p6 = av1.z ? __expf(wv) : 0.f;
            sc = s1v + sv1.w; wv = fmaxf(sc, 0.2f * sc); p7 = av1.w ? __expf(wv) : 0.f;
            dsum += ((p0 + p1) + (p2 + p3)) + ((p4 + p5) + (p6 + p7));
            frag pk;
            pk[0] = (short)bf16u(p0); pk[1] = (short)bf16u(p1);
            pk[2] = (short)bf16u(p2); pk[3] = (short)bf16u(p3);
            pk[4] = (short)bf16u(p4); pk[5] = (short)bf16u(p5);
            pk[6] = (short)bf16u(p6); pk[7] = (short)bf16u(p7);
            *reinterpret_cast<frag*>(&P[buf][m][cg * 8]) = pk;
        }

        lds_barrier();

        // ---- consume: 4 k-steps x (2 A-halves x 2 B-frags) = 16 MFMA/wave ----
        __builtin_amdgcn_s_setprio(1);
#pragma unroll
        for (int kk = 0; kk < 4; kk++) {
            frag a0 = *reinterpret_cast<const frag*>(&P[buf][lm][kk * 32 + q * 8]);
            frag a1 = *reinterpret_cast<const frag*>(&P[buf][16 + lm][kk * 32 + q * 8]);
#pragma unroll
            for (int nt = 0; nt < 2; nt++) {
                acc[0][nt] = __builtin_amdgcn_mfma_f32_16x16x32_bf16(a0, bf[kk * 2 + nt], acc[0][nt], 0, 0, 0);
                acc[1][nt] = __builtin_amdgcn_mfma_f32_16x16x32_bf16(a1, bf[kk * 2 + nt], acc[1][nt], 0, 0, 0);
            }
        }
        __builtin_amdgcn_s_setprio(0);
    }
#undef STAGE

    // denom partial: lanes with same m are cg=0..15 -> reduce over cg
    float v = dsum;
    v += __shfl_xor(v, 1); v += __shfl_xor(v, 2);
    v += __shfl_xor(v, 4); v += __shfl_xor(v, 8);
    if (cg == 0) denom4[(size_t)q4 * NN + i0 + m] = v;

    // U4 partial: plain stores (no atomics)
    float* Ub = U4 + (size_t)q4 * NN * HID;
#pragma unroll
    for (int h = 0; h < 2; h++)
#pragma unroll
        for (int nt = 0; nt < 2; nt++)
#pragma unroll
            for (int r = 0; r < 4; r++)
                Ub[(size_t)(i0 + h * 16 + q * 4 + r) * HID + w * 32 + nt * 16 + lm] = acc[h][nt][r];
}

// ---------------- normalize: out = (sum_q U4) / (sum_q denom4) ----------------
__global__ __launch_bounds__(256) void k_norm(const float* __restrict__ U4,
                                              const float* __restrict__ denom4,
                                              float* __restrict__ out) {
    int i = blockIdx.x, t = threadIdx.x;
    size_t S = (size_t)NN * HID;
    size_t base = (size_t)i * HID + t;
    float u = U4[base] + U4[base + S] + U4[base + 2 * S] + U4[base + 3 * S];
    float d = denom4[i] + denom4[i + NN] + denom4[i + 2 * NN] + denom4[i + 3 * NN];
    out[base] = (d != 0.f) ? u / d : 0.f;
}

extern "C" void kernel_launch(void* const* d_in, const int* in_sizes, int n_in,
                              void* d_out, int out_size, void* d_ws, size_t ws_size,
                              hipStream_t stream) {
    const float* X      = (const float*)d_in[0];   // 6144x1024
    const float* W      = (const float*)d_in[1];   // 1024x256
    const float* a_edge = (const float*)d_in[2];   // 512
    const int*   adj    = (const int*)d_in[3];     // 6144x6144
    float* out = (float*)d_out;

    float* U4     = (float*)d_ws;                          // 4*NN*HID f32 (25.2 MB)
    float* denom4 = U4 + (size_t)4 * NN * HID;             // 4*NN
    float* s1     = denom4 + (size_t)4 * NN;               // NN
    float* s2     = s1 + NN;                               // NN
    unsigned short* hT = (unsigned short*)(s2 + NN);       // HID*NN bf16 (3.1 MB)
    unsigned short* Wt = hT + (size_t)HID * NN;            // HID*INPUT bf16 (0.5 MB)
    // Xb (12.6 MB) ALIASES U4: dead before k_attn fully overwrites U4.
    unsigned short* Xb = (unsigned short*)U4;

    hipMemsetAsync(s1, 0, 2 * NN * sizeof(float), stream);
    k_prep<<<3072 + INPUT * HID / 256, 256, 0, stream>>>(X, W, Xb, Wt);
    k_gemm1<<<dim3(NN / 32, HID / 64), 256, 0, stream>>>(Xb, Wt, a_edge, hT, s1, s2);
    k_attn<<<dim3(NN / 32, 4), 512, 0, stream>>>(adj, s1, s2, hT, U4, denom4);
    k_norm<<<NN, 256, 0, stream>>>(U4, denom4, out);
}

// Round 7
// 290.371 us; speedup vs baseline: 1.3409x; 1.0579x over previous
//
#include <hip/hip_runtime.h>
#include <hip/hip_bf16.h>

#define NN 6144
#define INPUT 1024
#define HID 256

using frag  = __attribute__((ext_vector_type(8))) short;   // 8 bf16
using f32x4 = __attribute__((ext_vector_type(4))) float;

static __device__ __forceinline__ unsigned short bf16u(float x) {
    unsigned u = __float_as_uint(x);
    u += 0x7fff + ((u >> 16) & 1);     // RNE
    return (unsigned short)(u >> 16);
}

// async global->LDS (no VGPR dest; compiler cannot sink; gated by OUR counted vmcnt)
static __device__ __forceinline__ void gll16(const void* g, void* l) {
    __builtin_amdgcn_global_load_lds((__attribute__((address_space(1))) const void*)g,
                                     (__attribute__((address_space(3))) void*)l, 16, 0, 0);
}
static __device__ __forceinline__ void gll4(const void* g, void* l) {
    __builtin_amdgcn_global_load_lds((__attribute__((address_space(1))) const void*)g,
                                     (__attribute__((address_space(3))) void*)l, 4, 0, 0);
}

// LDS-producer barrier without the __syncthreads vmcnt(0) drain.
static __device__ __forceinline__ void lds_barrier() {
    asm volatile("s_waitcnt lgkmcnt(0)" ::: "memory");
    __builtin_amdgcn_s_barrier();
    __builtin_amdgcn_sched_barrier(0);
}

// ============ FRAG-ORDER TILE LAYOUT ============
// A 16x32 bf16 operand tile (16 rows x 32 k) is stored as 1 KB where 16-B slot l
// holds exactly MFMA lane l's fragment: row = l&15, k = (l>>4)*8 .. +7.
// -> every operand load is ONE dense 1KB wave read (16 cache lines) instead of
//    64 scattered 16B segments across 16 rows (the r0-r6 invariant bottleneck).

// ---------------- prep: X -> Xbp (frag tiles), W -> Wtp (frag tiles) ----------------
// Xbp tile (tm, tk) at (tm*32+tk)*512 ushorts: [i = tm*16 + (l&15)][k = tk*32 + (l>>4)*8..]
// Wtp tile (tn, tk) at (tn*32+tk)*512 ushorts: [n = tn*16 + (l&15)][k = ...]
__global__ __launch_bounds__(256) void k_prep(const float* __restrict__ X,
                                              const float* __restrict__ W,
                                              unsigned short* __restrict__ Xbp,
                                              unsigned short* __restrict__ Wtp) {
    int b = blockIdx.x;
    if (b < 3072) {                         // X: 6144 x 1024, thread -> (i, k8)
        int t = b * 256 + threadIdx.x;
        int i = t >> 7, k8 = t & 127;       // k = k8*8
        const float4* p = reinterpret_cast<const float4*>(X + (size_t)i * INPUT + k8 * 8);
        float4 x0 = p[0], x1 = p[1];
        frag v;
        v[0] = (short)bf16u(x0.x); v[1] = (short)bf16u(x0.y);
        v[2] = (short)bf16u(x0.z); v[3] = (short)bf16u(x0.w);
        v[4] = (short)bf16u(x1.x); v[5] = (short)bf16u(x1.y);
        v[6] = (short)bf16u(x1.z); v[7] = (short)bf16u(x1.w);
        size_t off = ((size_t)((i >> 4) * 32 + (k8 >> 2))) * 512 + (k8 & 3) * 128 + (i & 15) * 8;
        *reinterpret_cast<frag*>(Xbp + off) = v;
    } else {                                // W: 1024 x 256, thread -> (n, k8)
        int u = (b - 3072) * 256 + threadIdx.x;   // 32768 threads
        int n = u >> 7, k8 = u & 127;
        int k = k8 * 8;
        frag v;
#pragma unroll
        for (int e = 0; e < 8; e++) v[e] = (short)bf16u(W[(size_t)(k + e) * HID + n]);
        size_t off = ((size_t)((n >> 4) * 32 + (k8 >> 2))) * 512 + (k8 & 3) * 128 + (n & 15) * 8;
        *reinterpret_cast<frag*>(Wtp + off) = v;
    }
}

// ---------------- GEMM1: hTp = frag-order (X @ W)^T, + fused s1/s2 ----------------
// LDS-FREE. grid (192,4); block 256 = 4 waves, independent. Wave: M=32 (2 A-tiles),
// N=16 (tile tn = by*4+w), K=1024 = 32 frag-tiles. ALL reads are dense 1KB wave
// loads, sequential in tk. 3-set rotated register pipeline (depth 2), ~70 VGPR
// under a 128 cap -> allocator has headroom, nothing gets sunk.
__global__ __launch_bounds__(256, 4) void k_gemm1(const unsigned short* __restrict__ Xbp,
                                                  const unsigned short* __restrict__ Wtp,
                                                  const float* __restrict__ a_edge,
                                                  unsigned short* __restrict__ hTp,
                                                  float* __restrict__ s1,
                                                  float* __restrict__ s2) {
    int t = threadIdx.x;
    int w = t >> 6, l = t & 63, lm = l & 15, q = l >> 4;
    int bx = blockIdx.x, by = blockIdx.y;
    int i0 = bx * 32;
    int tn = by * 4 + w;

    const unsigned short* pA0 = Xbp + (size_t)(bx * 2) * 32 * 512 + l * 8;
    const unsigned short* pA1 = Xbp + (size_t)(bx * 2 + 1) * 32 * 512 + l * 8;
    const unsigned short* pB  = Wtp + (size_t)tn * 32 * 512 + l * 8;

    f32x4 acc0 = {}, acc1 = {};
    frag a0s[3], a1s[3], bs[3];
#pragma unroll
    for (int s = 0; s < 2; s++) {           // prologue: tk = 0, 1
        a0s[s] = *reinterpret_cast<const frag*>(pA0 + s * 512);
        a1s[s] = *reinterpret_cast<const frag*>(pA1 + s * 512);
        bs[s]  = *reinterpret_cast<const frag*>(pB  + s * 512);
    }
#pragma unroll
    for (int tk = 0; tk < 32; tk++) {
        int cur = tk % 3;
        if (tk < 30) {
            int nx = (tk + 2) % 3;
            a0s[nx] = *reinterpret_cast<const frag*>(pA0 + (tk + 2) * 512);
            a1s[nx] = *reinterpret_cast<const frag*>(pA1 + (tk + 2) * 512);
            bs[nx]  = *reinterpret_cast<const frag*>(pB  + (tk + 2) * 512);
        }
        acc0 = __builtin_amdgcn_mfma_f32_16x16x32_bf16(a0s[cur], bs[cur], acc0, 0, 0, 0);
        acc1 = __builtin_amdgcn_mfma_f32_16x16x32_bf16(a1s[cur], bs[cur], acc1, 0, 0, 0);
    }

    // hTp write in frag-tile order: tile (tj = bx, tn). Lane (lm,q), half h holds
    // C[j = i0 + h*16 + q*4 + r][n = tn*16 + lm] -> slot (h*2+(q>>1))*16+lm, e=(q&1)*4+r
    unsigned short* tb = hTp + ((size_t)bx * 16 + tn) * 512;
    ushort4 o;
    o.x = bf16u(acc0[0]); o.y = bf16u(acc0[1]); o.z = bf16u(acc0[2]); o.w = bf16u(acc0[3]);
    *reinterpret_cast<ushort4*>(tb + (q >> 1) * 128 + lm * 8 + (q & 1) * 4) = o;
    o.x = bf16u(acc1[0]); o.y = bf16u(acc1[1]); o.z = bf16u(acc1[2]); o.w = bf16u(acc1[3]);
    *reinterpret_cast<ushort4*>(tb + (2 + (q >> 1)) * 128 + lm * 8 + (q & 1) * 4) = o;

    // fused s1/s2: reduce over the 16 n of this wave's tile, few atomics
    float a1v = a_edge[tn * 16 + lm], a2v = a_edge[HID + tn * 16 + lm];
#pragma unroll
    for (int h = 0; h < 2; h++) {
        const f32x4& ac = h ? acc1 : acc0;
#pragma unroll
        for (int r = 0; r < 4; r++) {
            float v1 = ac[r] * a1v, v2 = ac[r] * a2v;
            v1 += __shfl_xor(v1, 1); v2 += __shfl_xor(v2, 1);
            v1 += __shfl_xor(v1, 2); v2 += __shfl_xor(v2, 2);
            v1 += __shfl_xor(v1, 4); v2 += __shfl_xor(v2, 4);
            v1 += __shfl_xor(v1, 8); v2 += __shfl_xor(v2, 8);
            if (lm == 0) {
                atomicAdd(&s1[i0 + h * 16 + q * 4 + r], v1);
                atomicAdd(&s2[i0 + h * 16 + q * 4 + r], v2);
            }
        }
    }
}

// ---------------- fused attention ----------------
// r6 skeleton (gll-staged adj/s2, counted vmcnt, P double-buffer) but bf B-frags
// now read DENSE from frag-order hTp: 8 x 1KB contiguous wave loads per chunk
// (16 lines each) instead of 8 x 64-way scattered 16B gathers -- removing the
// ~60us/dispatch of L1 request processing that was invariant across r0-r6.
__global__ __launch_bounds__(512, 2) void k_attn(const int* __restrict__ adj,
                                                 const float* __restrict__ s1,
                                                 const float* __restrict__ s2,
                                                 const unsigned short* __restrict__ hTp,
                                                 float* __restrict__ U4,
                                                 float* __restrict__ denom4) {
    __shared__ unsigned short P[2][32][136];   // 17408 B
    __shared__ int   adjS[2][32][128];         // 32768 B, linear (gll dest)
    __shared__ float s2S[2][128];              // 1024 B
    int t = threadIdx.x;
    int m = t >> 4, cg = t & 15;               // builder: row m (0..31), col-group cg
    int i0 = blockIdx.x * 32;
    int q4 = blockIdx.y, j0 = q4 * 1536;
    int w = t >> 6, l = t & 63, lm = l & 15, q = l >> 4;

    float s1v = s1[i0 + m];
    // staging: wave w stages adj rows w*4..w*4+3 (2 instrs x 2 rows) + 16 s2 floats
    const int*   astage = adj + (size_t)(i0 + w * 4 + (l >> 5)) * NN + j0 + (l & 31) * 4;
    const float* sstage = s2 + j0 + w * 16 + l;    // only lanes l<16 issue

    // dense B-frag base: tile (tj, tn = w*2+nt) at (tj*16 + tn)*512 + l*8 ushorts
    const unsigned short* hb = hTp + (size_t)(w * 2) * 512 + l * 8;
    int tjb = q4 * 48;                             // global j-tile base for this quarter

    f32x4 acc[2][2] = {};
    float dsum = 0.f;

#define STAGE(JC, BUF) { \
        gll16(astage + (JC), &adjS[BUF][w * 4][0]); \
        gll16(astage + (JC) + 2 * NN, &adjS[BUF][w * 4 + 2][0]); \
        if (l < 16) gll4(sstage + (JC), &s2S[BUF][w * 16]); }

    STAGE(0, 0)

    for (int c = 0; c < 12; c++) {
        int buf = c & 1, jc = c * 128;

        // ---- this chunk's 8 B-frags: DENSE 1KB wave loads ----
        frag bf[8];
#pragma unroll
        for (int kk = 0; kk < 4; kk++)
#pragma unroll
            for (int nt = 0; nt < 2; nt++)
                bf[kk * 2 + nt] = *reinterpret_cast<const frag*>(
                    hb + ((size_t)(tjb + c * 4 + kk) * 16 + nt) * 512);

        // outstanding: gll(c)[3, oldest] + bf[8] = 11 -> vmcnt(8) retires exactly gll(c)
        asm volatile("s_waitcnt vmcnt(8)" ::: "memory");
        __builtin_amdgcn_s_barrier();              // adjS[buf]/s2S[buf] ready block-wide
        __builtin_amdgcn_sched_barrier(0);
        if (c < 11) STAGE(jc + 128, buf ^ 1)       // after barrier: prev readers done

        // ---- build P[buf] from staged LDS (VALU only, no global waits) ----
        {
            const int*   aL = &adjS[buf][m][cg * 8];
            const float* sL = &s2S[buf][cg * 8];
            int4   av0 = *reinterpret_cast<const int4*>(aL);
            int4   av1 = *reinterpret_cast<const int4*>(aL + 4);
            float4 sv0 = *reinterpret_cast<const float4*>(sL);
            float4 sv1 = *reinterpret_cast<const float4*>(sL + 4);
            float sc, wv, p0, p1, p2, p3, p4, p5, p6, p7;
            sc = s1v + sv0.x; wv = fmaxf(sc, 0.2f * sc); p0 = av0.x ? __expf(wv) : 0.f;
            sc = s1v + sv0.y; wv = fmaxf(sc, 0.2f * sc); p1 = av0.y ? __expf(wv) : 0.f;
            sc = s1v + sv0.z; wv = fmaxf(sc, 0.2f * sc); p2 = av0.z ? __expf(wv) : 0.f;
            sc = s1v + sv0.w; wv = fmaxf(sc, 0.2f * sc); p3 = av0.w ? __expf(wv) : 0.f;
            sc = s1v + sv1.x; wv = fmaxf(sc, 0.2f * sc); p4 = av1.x ? __expf(wv) : 0.f;
            sc = s1v + sv1.y; wv = fmaxf(sc, 0.2f * sc); p5 = av1.y ? __expf(wv) : 0.f;
            sc = s1v + sv1.z; wv = fmaxf(sc, 0.2f * sc); p6 = av1.z ? __expf(wv) : 0.f;
            sc = s1v + sv1.w; wv = fmaxf(sc, 0.2f * sc); p7 = av1.w ? __expf(wv) : 0.f;
            dsum += ((p0 + p1) + (p2 + p3)) + ((p4 + p5) + (p6 + p7));
            frag pk;
            pk[0] = (short)bf16u(p0); pk[1] = (short)bf16u(p1);
            pk[2] = (short)bf16u(p2); pk[3] = (short)bf16u(p3);
            pk[4] = (short)bf16u(p4); pk[5] = (short)bf16u(p5);
            pk[6] = (short)bf16u(p6); pk[7] = (short)bf16u(p7);
            *reinterpret_cast<frag*>(&P[buf][m][cg * 8]) = pk;
        }

        lds_barrier();

        // ---- consume: 4 k-steps x (2 A-halves x 2 B-frags) = 16 MFMA/wave ----
        __builtin_amdgcn_s_setprio(1);
#pragma unroll
        for (int kk = 0; kk < 4; kk++) {
            frag a0 = *reinterpret_cast<const frag*>(&P[buf][lm][kk * 32 + q * 8]);
            frag a1 = *reinterpret_cast<const frag*>(&P[buf][16 + lm][kk * 32 + q * 8]);
#pragma unroll
            for (int nt = 0; nt < 2; nt++) {
                acc[0][nt] = __builtin_amdgcn_mfma_f32_16x16x32_bf16(a0, bf[kk * 2 + nt], acc[0][nt], 0, 0, 0);
                acc[1][nt] = __builtin_amdgcn_mfma_f32_16x16x32_bf16(a1, bf[kk * 2 + nt], acc[1][nt], 0, 0, 0);
            }
        }
        __builtin_amdgcn_s_setprio(0);
    }
#undef STAGE

    // denom partial: lanes with same m are cg=0..15 -> reduce over cg
    float v = dsum;
    v += __shfl_xor(v, 1); v += __shfl_xor(v, 2);
    v += __shfl_xor(v, 4); v += __shfl_xor(v, 8);
    if (cg == 0) denom4[(size_t)q4 * NN + i0 + m] = v;

    // U4 partial: plain stores (64B-dense per 16-lane group)
    float* Ub = U4 + (size_t)q4 * NN * HID;
#pragma unroll
    for (int h = 0; h < 2; h++)
#pragma unroll
        for (int nt = 0; nt < 2; nt++)
#pragma unroll
            for (int r = 0; r < 4; r++)
                Ub[(size_t)(i0 + h * 16 + q * 4 + r) * HID + w * 32 + nt * 16 + lm] = acc[h][nt][r];
}

// ---------------- normalize: out = (sum_q U4) / (sum_q denom4) ----------------
__global__ __launch_bounds__(256) void k_norm(const float* __restrict__ U4,
                                              const float* __restrict__ denom4,
                                              float* __restrict__ out) {
    int i = blockIdx.x, t = threadIdx.x;
    size_t S = (size_t)NN * HID;
    size_t base = (size_t)i * HID + t;
    float u = U4[base] + U4[base + S] + U4[base + 2 * S] + U4[base + 3 * S];
    float d = denom4[i] + denom4[i + NN] + denom4[i + 2 * NN] + denom4[i + 3 * NN];
    out[base] = (d != 0.f) ? u / d : 0.f;
}

extern "C" void kernel_launch(void* const* d_in, const int* in_sizes, int n_in,
                              void* d_out, int out_size, void* d_ws, size_t ws_size,
                              hipStream_t stream) {
    const float* X      = (const float*)d_in[0];   // 6144x1024
    const float* W      = (const float*)d_in[1];   // 1024x256
    const float* a_edge = (const float*)d_in[2];   // 512
    const int*   adj    = (const int*)d_in[3];     // 6144x6144
    float* out = (float*)d_out;

    float* U4     = (float*)d_ws;                          // 4*NN*HID f32 (25.2 MB)
    float* denom4 = U4 + (size_t)4 * NN * HID;             // 4*NN
    float* s1     = denom4 + (size_t)4 * NN;               // NN
    float* s2     = s1 + NN;                               // NN
    unsigned short* hTp = (unsigned short*)(s2 + NN);      // 192*16 frag tiles (3.1 MB)
    unsigned short* Wtp = hTp + (size_t)HID * NN;          // 16*32 frag tiles (0.5 MB)
    // Xbp (12.6 MB) ALIASES U4: dead before k_attn fully overwrites U4.
    unsigned short* Xbp = (unsigned short*)U4;

    hipMemsetAsync(s1, 0, 2 * NN * sizeof(float), stream);
    k_prep<<<3072 + 128, 256, 0, stream>>>(X, W, Xbp, Wtp);
    k_gemm1<<<dim3(NN / 32, 4), 256, 0, stream>>>(Xbp, Wtp, a_edge, hTp, s1, s2);
    k_attn<<<dim3(NN / 32, 4), 512, 0, stream>>>(adj, s1, s2, hTp, U4, denom4);
    k_norm<<<NN, 256, 0, stream>>>(U4, denom4, out);
}